// Round 7
// baseline (133.559 us; speedup 1.0000x reference)
//
#include <hip/hip_runtime.h>
#include <math.h>

#define SEQ   100
#define BATCH 256
#define NREP  8
#define FFD   2048
#define COL   (SEQ * BATCH * 4)   // floats per state buffer
#define RSQRT2 0.70710678118654752440f

__device__ __forceinline__ float wsum(float v) {
#pragma unroll
  for (int o = 32; o > 0; o >>= 1) v += __shfl_xor(v, o, 64);
  return v;
}

// ---------------------------------------------------------------- stage A
__global__ __launch_bounds__(64) void k_stageA(
    const float* __restrict__ x, const float* __restrict__ convw,
    const float* __restrict__ convb, const float* __restrict__ Wl,
    const float* __restrict__ bl, const float* __restrict__ lng,
    const float* __restrict__ lnb, float* __restrict__ xG)
{
  const int b = blockIdx.x;
  const int lane = threadIdx.x;
  const bool act = lane < 50;

  const float cw = convw[0], cb = convb[0];
  float W[4][4], B[4];
#pragma unroll
  for (int j = 0; j < 4; ++j) {
    B[j] = bl[j];
#pragma unroll
    for (int d = 0; d < 4; ++d) W[j][d] = Wl[j * 4 + d];
  }
  float h[2][4] = {{0.f,0.f,0.f,0.f},{0.f,0.f,0.f,0.f}};
  float gg[2][4] = {{0.f}}, eb[2][4] = {{0.f}};
  if (act) {
#pragma unroll
    for (int p = 0; p < 2; ++p) {
      const int r = lane * 2 + p;
      float4 xr = *(const float4*)(x + (b * SEQ + r) * 4);
      h[p][0] = fmaf(xr.x, cw, cb); h[p][1] = fmaf(xr.y, cw, cb);
      h[p][2] = fmaf(xr.z, cw, cb); h[p][3] = fmaf(xr.w, cw, cb);
      float4 gv = *(const float4*)(lng + r * 4);
      float4 bv = *(const float4*)(lnb + r * 4);
      gg[p][0] = gv.x; gg[p][1] = gv.y; gg[p][2] = gv.z; gg[p][3] = gv.w;
      eb[p][0] = bv.x; eb[p][1] = bv.y; eb[p][2] = bv.z; eb[p][3] = bv.w;
    }
  }
  for (int it = 0; it < NREP; ++it) {
    float y[2][4] = {{0.f,0.f,0.f,0.f},{0.f,0.f,0.f,0.f}};
    float s1 = 0.f, s2 = 0.f;
    if (act) {
#pragma unroll
      for (int p = 0; p < 2; ++p)
#pragma unroll
        for (int j = 0; j < 4; ++j) {
          float yy = B[j];
#pragma unroll
          for (int d = 0; d < 4; ++d) yy = fmaf(h[p][d], W[j][d], yy);
          y[p][j] = yy; s1 += yy; s2 = fmaf(yy, yy, s2);
        }
    }
    s1 = wsum(s1); s2 = wsum(s2);
    const float mean = s1 * (1.0f / 400.0f);
    const float var  = s2 * (1.0f / 400.0f) - mean * mean;
    const float rstd = rsqrtf(var + 1e-5f);
    if (act) {
#pragma unroll
      for (int p = 0; p < 2; ++p)
#pragma unroll
        for (int j = 0; j < 4; ++j) {
          float vv = fmaf((y[p][j] - mean) * rstd, gg[p][j], eb[p][j]);
          h[p][j] = 0.5f * vv * (1.0f + erff(vv * RSQRT2));
        }
    }
  }
  if (act) {
#pragma unroll
    for (int p = 0; p < 2; ++p) {
      const int r = lane * 2 + p;
      float yy[4];
#pragma unroll
      for (int j = 0; j < 4; ++j) {
        float a = B[j];
#pragma unroll
        for (int d = 0; d < 4; ++d) a = fmaf(h[p][d], W[j][d], a);
        yy[j] = a;
      }
      *(float4*)(xG + (r * BATCH + b) * 4) =
          make_float4(yy[0], yy[1], yy[2], yy[3]);
    }
  }
}

// ---------------------------------------------------------------- layer
// block = (column n, f-half fh); 200 blocks x 512 threads, 256 rows each.
// Reconstruct x = LN2(val0+val1) of prev layer; attn (redundant per half);
// FFN over own 1024 f; write val_half to global.
__global__ __launch_bounds__(512) void k_layer(
    const float* __restrict__ in0, const float* __restrict__ in1,
    const int first,
    const float* __restrict__ g2p, const float* __restrict__ e2p,
    float* __restrict__ vout,          // val[cur] base; +fh*COL inside
    const float* __restrict__ Wa,  const float* __restrict__ ba,
    const float* __restrict__ Wo,  const float* __restrict__ bo,
    const float* __restrict__ W1l, const float* __restrict__ b1l,
    const float* __restrict__ W2l, const float* __restrict__ b2l,
    const float* __restrict__ g1l, const float* __restrict__ e1l)
{
  const int n    = blockIdx.x;        // column 0..99
  const int fh   = blockIdx.y;        // f-half 0/1
  const int t    = threadIdx.x;       // 0..511
  const int lane = t & 63;
  const int wv   = t >> 6;            // 0..7
  const int h    = t >> 7;            // head (uniform per wave)
  const int qr0  = t & 127;           // first query row
  const int qr1  = qr0 + 128;         // second query row

  __shared__ __align__(16) float wbuf[512][12];  // 24 KB packed ffn weights
  __shared__ float2 kv[4][256];       // 8 KB
  __shared__ float  xs[256][4];       // 4 KB  current x
  __shared__ float  x1s[256][4];      // 4 KB  post-LN1
  __shared__ float  osm[4][256];      // 4 KB  attn out
  __shared__ float  pacc[4][256][4];  // 16 KB ffn partials (2-stage)
  __shared__ float  kred[8][2];

  // ---- issue ffn pass-0 staging loads (hide under reconstruct+attn)
  const int fbase = fh * 1024;
  float4 s_w1; float s_b1, s_w20, s_w21, s_w22, s_w23;
  {
    const int f = fbase + t;
    s_w1  = *(const float4*)(W1l + f * 4);
    s_b1  = b1l[f];
    s_w20 = W2l[f];           s_w21 = W2l[FFD + f];
    s_w22 = W2l[2 * FFD + f]; s_w23 = W2l[3 * FFD + f];
  }

  // ---- reconstruct x (threads 0..255, row t)
  if (t < 256) {
    if (first) {
      float4 a = *(const float4*)(in0 + (n * BATCH + t) * 4);
      xs[t][0] = a.x; xs[t][1] = a.y; xs[t][2] = a.z; xs[t][3] = a.w;
    } else {
      float4 a = *(const float4*)(in0 + (n * BATCH + t) * 4);
      float4 b = *(const float4*)(in1 + (n * BATCH + t) * 4);
      float v0 = a.x + b.x, v1 = a.y + b.y, v2 = a.z + b.z, v3 = a.w + b.w;
      const float mean = 0.25f * (v0 + v1 + v2 + v3);
      float d0 = v0-mean, d1 = v1-mean, d2 = v2-mean, d3 = v3-mean;
      const float var = 0.25f * (d0*d0 + d1*d1 + d2*d2 + d3*d3);
      const float rstd = rsqrtf(var + 1e-5f);
      xs[t][0] = fmaf(d0 * rstd, g2p[0], e2p[0]);
      xs[t][1] = fmaf(d1 * rstd, g2p[1], e2p[1]);
      xs[t][2] = fmaf(d2 * rstd, g2p[2], e2p[2]);
      xs[t][3] = fmaf(d3 * rstd, g2p[3], e2p[3]);
    }
  }
  __syncthreads();

  // ---- K,V for all 256 rows (thread: s = t&255, head pair pr = t>>8)
  {
    const int s = t & 255, pr = t >> 8;
    const float x0 = xs[s][0], x1 = xs[s][1], x2 = xs[s][2], x3 = xs[s][3];
#pragma unroll
    for (int i = 0; i < 2; ++i) {
      const int hh = pr * 2 + i;
      const float* wk = Wa + (4 + hh) * 4;
      const float* wp = Wa + (8 + hh) * 4;
      float k = ba[4+hh] + x0*wk[0] + x1*wk[1] + x2*wk[2] + x3*wk[3];
      float v = ba[8+hh] + x0*wp[0] + x1*wp[1] + x2*wp[2] + x3*wp[3];
      kv[hh][s] = make_float2(k, v);
    }
  }
  // ---- q for own two rows
  float q0, q1;
  {
    const float* wq = Wa + h * 4;
    q0 = ba[h] + xs[qr0][0]*wq[0] + xs[qr0][1]*wq[1]
               + xs[qr0][2]*wq[2] + xs[qr0][3]*wq[3];
    q1 = ba[h] + xs[qr1][0]*wq[0] + xs[qr1][1]*wq[1]
               + xs[qr1][2]*wq[2] + xs[qr1][3]*wq[3];
  }
  __syncthreads();

  // ---- per-head k max/min (waves 2h,2h+1 cover the head's 256 k)
  {
    float a = kv[h][qr0].x, c = kv[h][qr1].x;
    float mx = fmaxf(a, c), mn = fminf(a, c);
#pragma unroll
    for (int o = 32; o > 0; o >>= 1) {
      mx = fmaxf(mx, __shfl_xor(mx, o, 64));
      mn = fminf(mn, __shfl_xor(mn, o, 64));
    }
    if (lane == 0) { kred[wv][0] = mx; kred[wv][1] = mn; }
  }
  __syncthreads();

  // ---- attention: 2 queries per thread share the kv broadcast stream
  {
    const float kmx = fmaxf(kred[2*h][0], kred[2*h+1][0]);
    const float kmn = fminf(kred[2*h][1], kred[2*h+1][1]);
    const float m0 = (q0 >= 0.f) ? q0 * kmx : q0 * kmn;
    const float m1 = (q1 >= 0.f) ? q1 * kmx : q1 * kmn;
    float dA0=0.f,dA1=0.f,nA0=0.f,nA1=0.f;
    float dB0=0.f,dB1=0.f,nB0=0.f,nB1=0.f;
#pragma unroll 4
    for (int t2 = 0; t2 < 256; t2 += 2) {
      float4 kk = *(const float4*)&kv[h][t2];   // (k0,v0,k1,v1)
      float pA0 = __expf(fmaf(q0, kk.x, -m0));
      float pA1 = __expf(fmaf(q0, kk.z, -m0));
      float pB0 = __expf(fmaf(q1, kk.x, -m1));
      float pB1 = __expf(fmaf(q1, kk.z, -m1));
      dA0 += pA0; nA0 = fmaf(pA0, kk.y, nA0);
      dA1 += pA1; nA1 = fmaf(pA1, kk.w, nA1);
      dB0 += pB0; nB0 = fmaf(pB0, kk.y, nB0);
      dB1 += pB1; nB1 = fmaf(pB1, kk.w, nB1);
    }
    osm[h][qr0] = (nA0 + nA1) / (dA0 + dA1);
    osm[h][qr1] = (nB0 + nB1) / (dB0 + dB1);
  }
  __syncthreads();

  // ---- Wout proj + residual + LN1 (threads 0..255, full row in-thread)
  if (t < 256) {
    const float o0 = osm[0][t], o1 = osm[1][t], o2 = osm[2][t], o3 = osm[3][t];
    float rr[4];
#pragma unroll
    for (int d = 0; d < 4; ++d)
      rr[d] = xs[t][d] + bo[d] + o0*Wo[d*4+0] + o1*Wo[d*4+1]
                               + o2*Wo[d*4+2] + o3*Wo[d*4+3];
    const float mean = 0.25f * (rr[0] + rr[1] + rr[2] + rr[3]);
    float d0 = rr[0]-mean, d1 = rr[1]-mean, d2 = rr[2]-mean, d3 = rr[3]-mean;
    const float var = 0.25f * (d0*d0 + d1*d1 + d2*d2 + d3*d3);
    const float rstd = rsqrtf(var + 1e-5f);
    x1s[t][0] = fmaf(d0 * rstd, g1l[0], e1l[0]);
    x1s[t][1] = fmaf(d1 * rstd, g1l[1], e1l[1]);
    x1s[t][2] = fmaf(d2 * rstd, g1l[2], e1l[2]);
    x1s[t][3] = fmaf(d3 * rstd, g1l[3], e1l[3]);
  }
  __syncthreads();

  // ---- FFN: 2 passes of 512 f; wave wv covers 64 f/pass; lane rows
  //      {lane, lane+64, lane+128, lane+192}
  float xr[4][4];
#pragma unroll
  for (int rg = 0; rg < 4; ++rg) {
    const int s = rg * 64 + lane;
    xr[rg][0] = x1s[s][0]; xr[rg][1] = x1s[s][1];
    xr[rg][2] = x1s[s][2]; xr[rg][3] = x1s[s][3];
  }
  float acc[4][4] = {{0.f,0.f,0.f,0.f},{0.f,0.f,0.f,0.f},
                     {0.f,0.f,0.f,0.f},{0.f,0.f,0.f,0.f}};
  for (int p = 0; p < 2; ++p) {
    *(float4*)&wbuf[t][0] = s_w1;
    *(float4*)&wbuf[t][4] = make_float4(s_b1, s_w20, s_w21, s_w22);
    wbuf[t][8] = s_w23;
    if (p == 0) {       // issue pass-1 loads; hide under pass-0 compute
      const int f = fbase + 512 + t;
      s_w1  = *(const float4*)(W1l + f * 4);
      s_b1  = b1l[f];
      s_w20 = W2l[f];           s_w21 = W2l[FFD + f];
      s_w22 = W2l[2 * FFD + f]; s_w23 = W2l[3 * FFD + f];
    }
    __syncthreads();   // wbuf ready
    const int fb = __builtin_amdgcn_readfirstlane(wv) * 64;
#pragma unroll 4
    for (int j = 0; j < 64; ++j) {
      const int fl = fb + j;
      const float4 w1 = *(const float4*)&wbuf[fl][0];
      const float4 wb = *(const float4*)&wbuf[fl][4];  // {b1,w20,w21,w22}
      const float w23 = wbuf[fl][8];
#pragma unroll
      for (int rg = 0; rg < 4; ++rg) {
        float hh = fmaf(xr[rg][3], w1.w, fmaf(xr[rg][2], w1.z,
                   fmaf(xr[rg][1], w1.y, fmaf(xr[rg][0], w1.x, wb.x))));
        hh = fmaxf(hh, 0.f);
        acc[rg][0] = fmaf(hh, wb.y, acc[rg][0]);
        acc[rg][1] = fmaf(hh, wb.z, acc[rg][1]);
        acc[rg][2] = fmaf(hh, wb.w, acc[rg][2]);
        acc[rg][3] = fmaf(hh, w23, acc[rg][3]);
      }
    }
    __syncthreads();   // wbuf consumed; safe to overwrite next pass
  }

  // ---- pacc 2-stage accumulate: waves 0-3 write, waves 4-7 add
  if (wv < 4) {
#pragma unroll
    for (int rg = 0; rg < 4; ++rg)
      *(float4*)&pacc[wv][rg * 64 + lane][0] =
          make_float4(acc[rg][0], acc[rg][1], acc[rg][2], acc[rg][3]);
  }
  __syncthreads();
  if (wv >= 4) {
#pragma unroll
    for (int rg = 0; rg < 4; ++rg) {
      float4 o = *(float4*)&pacc[wv - 4][rg * 64 + lane][0];
      o.x += acc[rg][0]; o.y += acc[rg][1];
      o.z += acc[rg][2]; o.w += acc[rg][3];
      *(float4*)&pacc[wv - 4][rg * 64 + lane][0] = o;
    }
  }
  __syncthreads();

  // ---- val_half = 0.5*(x1s + b2) + sum(pacc) -> global
  if (t < 256) {
    float v[4];
#pragma unroll
    for (int d = 0; d < 4; ++d) {
      float s4 = 0.5f * (x1s[t][d] + b2l[d]);
#pragma unroll
      for (int w = 0; w < 4; ++w) s4 += pacc[w][t][d];
      v[d] = s4;
    }
    *(float4*)(vout + fh * COL + (n * BATCH + t) * 4) =
        make_float4(v[0], v[1], v[2], v[3]);
  }
}

// ---------------------------------------------------------------- final
// LN2(layer3) + final linear + softmax. block = column n, thread = row b.
__global__ __launch_bounds__(256) void k_fin(
    const float* __restrict__ in0, const float* __restrict__ in1,
    const float* __restrict__ g2p, const float* __restrict__ e2p,
    const float* __restrict__ Wl,  const float* __restrict__ bl,
    float* __restrict__ out)
{
  const int n = blockIdx.x, t = threadIdx.x;
  float4 a = *(const float4*)(in0 + (n * BATCH + t) * 4);
  float4 b = *(const float4*)(in1 + (n * BATCH + t) * 4);
  float v0 = a.x + b.x, v1 = a.y + b.y, v2 = a.z + b.z, v3 = a.w + b.w;
  const float mean = 0.25f * (v0 + v1 + v2 + v3);
  float d0 = v0-mean, d1 = v1-mean, d2 = v2-mean, d3 = v3-mean;
  const float var = 0.25f * (d0*d0 + d1*d1 + d2*d2 + d3*d3);
  const float rstd = rsqrtf(var + 1e-5f);
  float xf[4];
  xf[0] = fmaf(d0 * rstd, g2p[0], e2p[0]);
  xf[1] = fmaf(d1 * rstd, g2p[1], e2p[1]);
  xf[2] = fmaf(d2 * rstd, g2p[2], e2p[2]);
  xf[3] = fmaf(d3 * rstd, g2p[3], e2p[3]);
  float y[4];
#pragma unroll
  for (int j = 0; j < 4; ++j)
    y[j] = fmaf(xf[3], Wl[j*4+3], fmaf(xf[2], Wl[j*4+2],
           fmaf(xf[1], Wl[j*4+1], fmaf(xf[0], Wl[j*4+0], bl[j]))));
  float m = fmaxf(fmaxf(y[0], y[1]), fmaxf(y[2], y[3]));
  float e[4], ssum = 0.f;
#pragma unroll
  for (int j = 0; j < 4; ++j) { e[j] = __expf(y[j] - m); ssum += e[j]; }
  const float inv = 1.0f / ssum;
  *(float4*)(out + (t * SEQ + n) * 4) =
      make_float4(e[0]*inv, e[1]*inv, e[2]*inv, e[3]*inv);
}

// ---------------------------------------------------------------- launch
extern "C" void kernel_launch(void* const* d_in, const int* in_sizes, int n_in,
                              void* d_out, int out_size, void* d_ws, size_t ws_size,
                              hipStream_t stream)
{
  const float* x     = (const float*)d_in[0];
  const float* convw = (const float*)d_in[1];
  const float* convb = (const float*)d_in[2];
  const float* Wl    = (const float*)d_in[3];
  const float* bl    = (const float*)d_in[4];
  const float* lng   = (const float*)d_in[5];
  const float* lnb   = (const float*)d_in[6];
  const float* Win   = (const float*)d_in[7];
  const float* bi    = (const float*)d_in[8];
  const float* Wout  = (const float*)d_in[9];
  const float* bout  = (const float*)d_in[10];
  const float* W1    = (const float*)d_in[11];
  const float* b1    = (const float*)d_in[12];
  const float* W2    = (const float*)d_in[13];
  const float* b2    = (const float*)d_in[14];
  const float* g1    = (const float*)d_in[15];
  const float* be1   = (const float*)d_in[16];
  const float* g2    = (const float*)d_in[17];
  const float* be2   = (const float*)d_in[18];

  float* ws  = (float*)d_ws;
  float* xG  = ws;                    // [100][256][4]
  float* valA = ws + COL;             // parity 0: halves 0,1 (contiguous)
  float* valB = ws + 3 * COL;         // parity 1: halves 0,1

  k_stageA<<<BATCH, 64, 0, stream>>>(x, convw, convb, Wl, bl, lng, lnb, xG);

  for (int l = 0; l < 4; ++l) {
    float* cur        = (l & 1) ? valB : valA;
    const float* prev = (l & 1) ? valA : valB;
    const float* i0 = (l == 0) ? xG : prev;
    const float* i1 = (l == 0) ? xG : prev + COL;
    const int pl = (l == 0) ? 0 : l - 1;
    k_layer<<<dim3(SEQ, 2), 512, 0, stream>>>(
        i0, i1, (l == 0) ? 1 : 0,
        g2 + pl * 4, be2 + pl * 4, cur,
        Win + l * 48, bi + l * 12, Wout + l * 16, bout + l * 4,
        W1 + l * FFD * 4, b1 + l * FFD, W2 + l * 4 * FFD, b2 + l * 4,
        g1 + l * 4, be1 + l * 4);
  }
  k_fin<<<SEQ, 256, 0, stream>>>(valB, valB + COL, g2 + 12, be2 + 12,
                                 Wl, bl, (float*)d_out);
}

// Round 8
// 121.505 us; speedup vs baseline: 1.0992x; 1.0992x over previous
//
#include <hip/hip_runtime.h>
#include <math.h>

#define SEQ   100
#define BATCH 256
#define NREP  8
#define FFD   2048
#define RSQRT2 0.70710678118654752440f

__device__ __forceinline__ float wsum(float v) {
#pragma unroll
  for (int o = 32; o > 0; o >>= 1) v += __shfl_xor(v, o, 64);
  return v;
}

// ---------------------------------------------------------------- stage A
__global__ __launch_bounds__(64) void k_stageA(
    const float* __restrict__ x, const float* __restrict__ convw,
    const float* __restrict__ convb, const float* __restrict__ Wl,
    const float* __restrict__ bl, const float* __restrict__ lng,
    const float* __restrict__ lnb, float* __restrict__ XT)
{
  const int b = blockIdx.x;
  const int lane = threadIdx.x;
  const bool act = lane < 50;

  const float cw = convw[0], cb = convb[0];
  float W[4][4], B[4];
#pragma unroll
  for (int j = 0; j < 4; ++j) {
    B[j] = bl[j];
#pragma unroll
    for (int d = 0; d < 4; ++d) W[j][d] = Wl[j * 4 + d];
  }
  float h[2][4] = {{0.f,0.f,0.f,0.f},{0.f,0.f,0.f,0.f}};
  float gg[2][4] = {{0.f}}, eb[2][4] = {{0.f}};
  if (act) {
#pragma unroll
    for (int p = 0; p < 2; ++p) {
      const int r = lane * 2 + p;
      float4 xr = *(const float4*)(x + (b * SEQ + r) * 4);
      h[p][0] = fmaf(xr.x, cw, cb); h[p][1] = fmaf(xr.y, cw, cb);
      h[p][2] = fmaf(xr.z, cw, cb); h[p][3] = fmaf(xr.w, cw, cb);
      float4 gv = *(const float4*)(lng + r * 4);
      float4 bv = *(const float4*)(lnb + r * 4);
      gg[p][0] = gv.x; gg[p][1] = gv.y; gg[p][2] = gv.z; gg[p][3] = gv.w;
      eb[p][0] = bv.x; eb[p][1] = bv.y; eb[p][2] = bv.z; eb[p][3] = bv.w;
    }
  }
  for (int it = 0; it < NREP; ++it) {
    float y[2][4] = {{0.f,0.f,0.f,0.f},{0.f,0.f,0.f,0.f}};
    float s1 = 0.f, s2 = 0.f;
    if (act) {
#pragma unroll
      for (int p = 0; p < 2; ++p)
#pragma unroll
        for (int j = 0; j < 4; ++j) {
          float yy = B[j];
#pragma unroll
          for (int d = 0; d < 4; ++d) yy = fmaf(h[p][d], W[j][d], yy);
          y[p][j] = yy; s1 += yy; s2 = fmaf(yy, yy, s2);
        }
    }
    s1 = wsum(s1); s2 = wsum(s2);
    const float mean = s1 * (1.0f / 400.0f);
    const float var  = s2 * (1.0f / 400.0f) - mean * mean;
    const float rstd = rsqrtf(var + 1e-5f);
    if (act) {
#pragma unroll
      for (int p = 0; p < 2; ++p)
#pragma unroll
        for (int j = 0; j < 4; ++j) {
          float vv = fmaf((y[p][j] - mean) * rstd, gg[p][j], eb[p][j]);
          h[p][j] = 0.5f * vv * (1.0f + erff(vv * RSQRT2));
        }
    }
  }
  if (act) {
#pragma unroll
    for (int p = 0; p < 2; ++p) {
      const int r = lane * 2 + p;
      float yy[4];
#pragma unroll
      for (int j = 0; j < 4; ++j) {
        float a = B[j];
#pragma unroll
        for (int d = 0; d < 4; ++d) a = fmaf(h[p][d], W[j][d], a);
        yy[j] = a;
      }
      *(float4*)(XT + (r * BATCH + b) * 4) =
          make_float4(yy[0], yy[1], yy[2], yy[3]);
    }
  }
}

// ---------------------------------------------------------------- layer
// block = (column n, batch-half); 200 blocks x 1024 threads (16 waves).
// attn split over key-halves; FFN weights LDS-staged (4 passes of 512 f,
// 32 f per wave per pass); layer 3 also does final linear + softmax.
__global__ __launch_bounds__(1024, 4) void k_layer(
    const float* __restrict__ XTin, float* __restrict__ XTout,
    const float* __restrict__ Wa,  const float* __restrict__ ba,
    const float* __restrict__ Wo,  const float* __restrict__ bo,
    const float* __restrict__ W1l, const float* __restrict__ b1l,
    const float* __restrict__ W2l, const float* __restrict__ b2l,
    const float* __restrict__ g1l, const float* __restrict__ e1l,
    const float* __restrict__ g2l, const float* __restrict__ e2l,
    const float* __restrict__ Wl,  const float* __restrict__ bl,
    float* __restrict__ out, const int last)
{
  const int n      = blockIdx.x;        // column 0..99
  const int base_s = blockIdx.y * 128;  // batch half
  const int t      = threadIdx.x;       // 0..1023
  const int lane   = t & 63;
  const int wv     = t >> 6;            // 0..15
  const int h      = (t >> 7) & 3;      // head (wave-uniform)
  const int qr     = t & 127;           // query row within half
  const int kh     = t >> 9;            // key half (wave-uniform)

  __shared__ __align__(16) float wbuf[512][12]; // 24 KB packed ffn weights
  __shared__ float2 kv[4][256];        // 8 KB  full-column k,v per head
  __shared__ float2 part[4][128][2];   // 4 KB  attn partial den/num
  __shared__ float  osm[4][128];       // 2 KB  attn out
  __shared__ float  x1s[128][4];       // 2 KB  post-LN1 rows
  __shared__ float  pacc[8][128][4];   // 16 KB ffn partials (2-stage)
  __shared__ float  kred[4][4][2];

  // ---- issue ffn pass-0 staging loads (hide under kv+attn)
  float4 s_w1; float s_b1, s_w20, s_w21, s_w22, s_w23;
  if (t < 512) {
    const int f = t;
    s_w1  = *(const float4*)(W1l + f * 4);
    s_b1  = b1l[f];
    s_w20 = W2l[f];           s_w21 = W2l[FFD + f];
    s_w22 = W2l[2 * FFD + f]; s_w23 = W2l[3 * FFD + f];
  }

  // ---- K,V for the whole column: thread = (head = t>>8, s = t&255)
  {
    const int s = t & 255, hh = t >> 8;
    float4 xr = *(const float4*)(XTin + (n * BATCH + s) * 4);
    const float* wk = Wa + (4 + hh) * 4;
    const float* wp = Wa + (8 + hh) * 4;
    float k = ba[4+hh] + xr.x*wk[0] + xr.y*wk[1] + xr.z*wk[2] + xr.w*wk[3];
    float v = ba[8+hh] + xr.x*wp[0] + xr.y*wp[1] + xr.z*wp[2] + xr.w*wp[3];
    kv[hh][s] = make_float2(k, v);
  }
  // ---- q for own (h, qr) (computed redundantly by both kh threads)
  float q;
  {
    float4 xr = *(const float4*)(XTin + (n * BATCH + base_s + qr) * 4);
    const float* wq = Wa + h * 4;
    q = ba[h] + xr.x*wq[0] + xr.y*wq[1] + xr.z*wq[2] + xr.w*wq[3];
  }
  __syncthreads();

  // ---- per-head k max/min: wave wv covers strip of 64 keys of its head
  {
    const int strip = (wv >> 3) * 2 + (wv & 1);
    float k = kv[h][strip * 64 + lane].x;
    float mx = k, mn = k;
#pragma unroll
    for (int o = 32; o > 0; o >>= 1) {
      mx = fmaxf(mx, __shfl_xor(mx, o, 64));
      mn = fminf(mn, __shfl_xor(mn, o, 64));
    }
    if (lane == 0) { kred[h][strip][0] = mx; kred[h][strip][1] = mn; }
  }
  __syncthreads();

  // ---- attention: thread handles 128 keys [kh*128, kh*128+128)
  {
    const float kmx = fmaxf(fmaxf(kred[h][0][0], kred[h][1][0]),
                            fmaxf(kred[h][2][0], kred[h][3][0]));
    const float kmn = fminf(fminf(kred[h][0][1], kred[h][1][1]),
                            fminf(kred[h][2][1], kred[h][3][1]));
    const float m = (q >= 0.f) ? q * kmx : q * kmn;  // exact max_t(q*k_t)
    const int kb = kh * 128;
    float d0=0.f,d1=0.f,d2=0.f,d3=0.f,n0=0.f,n1=0.f,n2=0.f,n3=0.f;
#pragma unroll 4
    for (int i = 0; i < 128; i += 4) {
      float4 a = *(const float4*)&kv[h][kb + i];      // k0 v0 k1 v1
      float4 b = *(const float4*)&kv[h][kb + i + 2];  // k2 v2 k3 v3
      float p0 = __expf(fmaf(q, a.x, -m)); d0 += p0; n0 = fmaf(p0, a.y, n0);
      float p1 = __expf(fmaf(q, a.z, -m)); d1 += p1; n1 = fmaf(p1, a.w, n1);
      float p2 = __expf(fmaf(q, b.x, -m)); d2 += p2; n2 = fmaf(p2, b.y, n2);
      float p3 = __expf(fmaf(q, b.z, -m)); d3 += p3; n3 = fmaf(p3, b.w, n3);
    }
    part[h][qr][kh] = make_float2(d0+d1+d2+d3, n0+n1+n2+n3);
  }
  __syncthreads();

  // ---- combine key-halves (threads 0..511)
  if (t < 512) {
    float4 pp = *(const float4*)&part[t >> 7][t & 127][0]; // d0 n0 d1 n1
    osm[t >> 7][t & 127] = (pp.y + pp.w) / (pp.x + pp.z);
  }
  __syncthreads();

  // ---- Wout proj + residual + LN1 : threads 0..511 -> (r = t>>2, d = t&3)
  if (t < 512) {
    const int r = t >> 2, d = t & 3;
    const float o0 = osm[0][r], o1 = osm[1][r], o2 = osm[2][r], o3 = osm[3][r];
    float rr = XTin[(n * BATCH + base_s + r) * 4 + d] + bo[d]
             + o0*Wo[d*4+0] + o1*Wo[d*4+1] + o2*Wo[d*4+2] + o3*Wo[d*4+3];
    float sum = rr + __shfl_xor(rr, 1, 64); sum += __shfl_xor(sum, 2, 64);
    const float mean = 0.25f * sum;
    const float dv = rr - mean;
    float qq = dv * dv;
    float qs = qq + __shfl_xor(qq, 1, 64); qs += __shfl_xor(qs, 2, 64);
    const float rstd = rsqrtf(0.25f * qs + 1e-5f);
    x1s[r][d] = fmaf(dv * rstd, g1l[d], e1l[d]);
  }
  __syncthreads();

  // ---- FFN: 4 passes of 512 f; wave wv covers 32 f/pass; lane rows
  //      {lane, 64+lane}
  const float xA0 = x1s[lane][0],    xA1 = x1s[lane][1];
  const float xA2 = x1s[lane][2],    xA3 = x1s[lane][3];
  const float xB0 = x1s[64+lane][0], xB1 = x1s[64+lane][1];
  const float xB2 = x1s[64+lane][2], xB3 = x1s[64+lane][3];
  float aA0=0.f,aA1=0.f,aA2=0.f,aA3=0.f;
  float aB0=0.f,aB1=0.f,aB2=0.f,aB3=0.f;

  for (int p = 0; p < 4; ++p) {
    if (t < 512) {
      *(float4*)&wbuf[t][0] = s_w1;
      *(float4*)&wbuf[t][4] = make_float4(s_b1, s_w20, s_w21, s_w22);
      wbuf[t][8] = s_w23;
      if (p < 3) {     // issue next-pass loads; latency hides under compute
        const int f = (p + 1) * 512 + t;
        s_w1  = *(const float4*)(W1l + f * 4);
        s_b1  = b1l[f];
        s_w20 = W2l[f];           s_w21 = W2l[FFD + f];
        s_w22 = W2l[2 * FFD + f]; s_w23 = W2l[3 * FFD + f];
      }
    }
    __syncthreads();   // wbuf ready
    const int fb = __builtin_amdgcn_readfirstlane(wv) * 32;
#pragma unroll 4
    for (int j = 0; j < 32; ++j) {
      const int fl = fb + j;
      const float4 w1 = *(const float4*)&wbuf[fl][0];
      const float4 wb = *(const float4*)&wbuf[fl][4];  // {b1,w20,w21,w22}
      const float w23 = wbuf[fl][8];
      float hA = fmaf(xA3, w1.w, fmaf(xA2, w1.z, fmaf(xA1, w1.y, fmaf(xA0, w1.x, wb.x))));
      hA = fmaxf(hA, 0.f);
      aA0 = fmaf(hA, wb.y, aA0); aA1 = fmaf(hA, wb.z, aA1);
      aA2 = fmaf(hA, wb.w, aA2); aA3 = fmaf(hA, w23, aA3);
      float hB = fmaf(xB3, w1.w, fmaf(xB2, w1.z, fmaf(xB1, w1.y, fmaf(xB0, w1.x, wb.x))));
      hB = fmaxf(hB, 0.f);
      aB0 = fmaf(hB, wb.y, aB0); aB1 = fmaf(hB, wb.z, aB1);
      aB2 = fmaf(hB, wb.w, aB2); aB3 = fmaf(hB, w23, aB3);
    }
    __syncthreads();   // wbuf consumed
  }

  // ---- pacc 2-stage accumulate: waves 0-7 write, waves 8-15 add
  if (wv < 8) {
    *(float4*)&pacc[wv][lane][0]      = make_float4(aA0, aA1, aA2, aA3);
    *(float4*)&pacc[wv][64 + lane][0] = make_float4(aB0, aB1, aB2, aB3);
  }
  __syncthreads();
  if (wv >= 8) {
    float4 o = *(float4*)&pacc[wv - 8][lane][0];
    o.x += aA0; o.y += aA1; o.z += aA2; o.w += aA3;
    *(float4*)&pacc[wv - 8][lane][0] = o;
    float4 o2 = *(float4*)&pacc[wv - 8][64 + lane][0];
    o2.x += aB0; o2.y += aB1; o2.z += aB2; o2.w += aB3;
    *(float4*)&pacc[wv - 8][64 + lane][0] = o2;
  }
  __syncthreads();

  // ---- reduce + residual + LN2 : threads 0..511 -> (r, d)
  if (t < 512) {
    const int r = t >> 2, d = t & 3;
    float s8 = b2l[d];
#pragma unroll
    for (int w = 0; w < 8; ++w) s8 += pacc[w][r][d];
    float val = x1s[r][d] + s8;
    float sum = val + __shfl_xor(val, 1, 64); sum += __shfl_xor(sum, 2, 64);
    const float mean = 0.25f * sum;
    const float dv = val - mean;
    float qq = dv * dv;
    float qs = qq + __shfl_xor(qq, 1, 64); qs += __shfl_xor(qs, 2, 64);
    const float rstd = rsqrtf(0.25f * qs + 1e-5f);
    const float res = fmaf(dv * rstd, g2l[d], e2l[d]);
    if (!last) XTout[(n * BATCH + base_s + r) * 4 + d] = res;
    else       x1s[r][d] = res;   // own element: no race
  }

  // ---- layer 3 only: final linear + softmax over d
  if (last) {
    __syncthreads();
    if (t < 512) {
      const int r = t >> 2, j = t & 3;
      const float y = fmaf(x1s[r][3], Wl[j*4+3], fmaf(x1s[r][2], Wl[j*4+2],
                      fmaf(x1s[r][1], Wl[j*4+1], fmaf(x1s[r][0], Wl[j*4+0], bl[j]))));
      float mx = fmaxf(y, __shfl_xor(y, 1, 64)); mx = fmaxf(mx, __shfl_xor(mx, 2, 64));
      const float e = __expf(y - mx);
      float se = e + __shfl_xor(e, 1, 64); se += __shfl_xor(se, 2, 64);
      out[((base_s + r) * SEQ + n) * 4 + j] = e / se;
    }
  }
}

// ---------------------------------------------------------------- launch
extern "C" void kernel_launch(void* const* d_in, const int* in_sizes, int n_in,
                              void* d_out, int out_size, void* d_ws, size_t ws_size,
                              hipStream_t stream)
{
  const float* x     = (const float*)d_in[0];
  const float* convw = (const float*)d_in[1];
  const float* convb = (const float*)d_in[2];
  const float* Wl    = (const float*)d_in[3];
  const float* bl    = (const float*)d_in[4];
  const float* lng   = (const float*)d_in[5];
  const float* lnb   = (const float*)d_in[6];
  const float* Win   = (const float*)d_in[7];
  const float* bi    = (const float*)d_in[8];
  const float* Wout  = (const float*)d_in[9];
  const float* bout  = (const float*)d_in[10];
  const float* W1    = (const float*)d_in[11];
  const float* b1    = (const float*)d_in[12];
  const float* W2    = (const float*)d_in[13];
  const float* b2    = (const float*)d_in[14];
  const float* g1    = (const float*)d_in[15];
  const float* be1   = (const float*)d_in[16];
  const float* g2    = (const float*)d_in[17];
  const float* be2   = (const float*)d_in[18];

  float* XT0 = (float*)d_ws;            // [100][256][4]
  float* XT1 = XT0 + SEQ * BATCH * 4;

  k_stageA<<<BATCH, 64, 0, stream>>>(x, convw, convb, Wl, bl, lng, lnb, XT0);
  for (int l = 0; l < 4; ++l) {
    const float* in  = (l & 1) ? XT1 : XT0;
    float*       outb= (l & 1) ? XT0 : XT1;
    k_layer<<<dim3(SEQ, 2), 1024, 0, stream>>>(
        in, outb,
        Win + l * 48, bi + l * 12, Wout + l * 16, bout + l * 4,
        W1 + l * FFD * 4, b1 + l * FFD, W2 + l * 4 * FFD, b2 + l * 4,
        g1 + l * 4, be1 + l * 4, g2 + l * 4, be2 + l * 4,
        Wl, bl, (float*)d_out, (l == 3) ? 1 : 0);
  }
}